// Round 1
// baseline (935.494 us; speedup 1.0000x reference)
//
#include <hip/hip_runtime.h>

typedef __bf16 bf16;
typedef __bf16 bf16x4 __attribute__((ext_vector_type(4)));
typedef __bf16 bf16x8 __attribute__((ext_vector_type(8)));
typedef float f32x4 __attribute__((ext_vector_type(4)));

#define MFMA(a, b, c) __builtin_amdgcn_mfma_f32_16x16x32_bf16((a), (b), (c), 0, 0, 0)

// ---------------- prep: out[c][r] = bf16(in[r][c]) ----------------
__global__ void transpose_cast(const float* __restrict__ in, bf16* __restrict__ out,
                               int R, int C) {
  int i = blockIdx.x * 256 + threadIdx.x;
  if (i >= R * C) return;
  int r = i / C, c = i - r * C;
  out[(size_t)c * R + r] = (bf16)in[i];
}

// ---------------- GEMM: C[M][N] = A[M][K] @ Bt[N][K]^T + bias[N] ----------------
// 128x128 tile, BK=32, 4 waves (2x2), each wave 64x64 via 4x4 16x16x32 MFMA frags.
template <bool AF32>
__global__ __launch_bounds__(256) void gemm_bt_bias(
    const void* __restrict__ Ap, const bf16* __restrict__ Bt,
    const float* __restrict__ bias, float* __restrict__ C,
    int M, int N, int K) {
  __shared__ bf16 lA[128 * 32];
  __shared__ bf16 lB[128 * 32];
  const int t = threadIdx.x, l = t & 63;
  const int w = t >> 6, wr = w >> 1, wc = w & 1;
  const int li = l & 15, kl = (l >> 4) << 3;
  const long bm0 = (long)blockIdx.x * 128, bn0 = (long)blockIdx.y * 128;
  f32x4 acc[4][4] = {};
  for (int ks = 0; ks < (K >> 5); ++ks) {
    const int k0 = ks << 5;
    __syncthreads();
#pragma unroll
    for (int i = 0; i < 2; ++i) {
      int u = t + (i << 8);           // 16B unit within the 128x32 tile
      int row = u >> 2, kc = (u & 3) << 3;
      if constexpr (AF32) {
        const float* ag = (const float*)Ap + (bm0 + row) * K + k0 + kc;
        f32x4 v0 = *((const f32x4*)ag);
        f32x4 v1 = *((const f32x4*)(ag + 4));
        bf16x8 pk;
        pk[0] = (bf16)v0[0]; pk[1] = (bf16)v0[1]; pk[2] = (bf16)v0[2]; pk[3] = (bf16)v0[3];
        pk[4] = (bf16)v1[0]; pk[5] = (bf16)v1[1]; pk[6] = (bf16)v1[2]; pk[7] = (bf16)v1[3];
        *((bf16x8*)&lA[u << 3]) = pk;
      } else {
        *((bf16x8*)&lA[u << 3]) =
            *((const bf16x8*)((const bf16*)Ap + (bm0 + row) * K + k0 + kc));
      }
      *((bf16x8*)&lB[u << 3]) = *((const bf16x8*)&Bt[(bn0 + row) * K + k0 + kc]);
    }
    __syncthreads();
    bf16x8 af[4], bfr[4];
#pragma unroll
    for (int mt = 0; mt < 4; ++mt)
      af[mt] = *((const bf16x8*)&lA[(wr * 64 + mt * 16 + li) * 32 + kl]);
#pragma unroll
    for (int nt = 0; nt < 4; ++nt)
      bfr[nt] = *((const bf16x8*)&lB[(wc * 64 + nt * 16 + li) * 32 + kl]);
#pragma unroll
    for (int mt = 0; mt < 4; ++mt)
#pragma unroll
      for (int nt = 0; nt < 4; ++nt)
        acc[mt][nt] = MFMA(af[mt], bfr[nt], acc[mt][nt]);
  }
#pragma unroll
  for (int mt = 0; mt < 4; ++mt)
#pragma unroll
    for (int nt = 0; nt < 4; ++nt) {
      long col = bn0 + wc * 64 + nt * 16 + li;
      float bv = bias[col];
#pragma unroll
      for (int r = 0; r < 4; ++r) {
        long row = bm0 + wr * 64 + mt * 16 + ((l >> 4) << 2) + r;
        C[row * N + col] = acc[mt][nt][r] + bv;
      }
    }
}

// ---------------- fused per-window qkv + attention ----------------
// grid = 2048 (one window per block), 256 threads = 4 waves.
// Per head: waves split the 192 head-cols (q|k|v) of the qkv GEMM, stage
// q (pre-scaled), k, v^T to LDS, then each wave owns a 16-row strip of S:
// QK^T -> in-register softmax (+rel-pos bias) -> P@V -> bf16 out.
__global__ __launch_bounds__(256) void fused_qkv_attn(
    const float* __restrict__ x, const bf16* __restrict__ w1t,
    const float* __restrict__ tbias, const float* __restrict__ rpb,
    bf16* __restrict__ attn_out) {
  __shared__ bf16 xs[64 * 520];   // x window, bf16, padded (stride 520)
  __shared__ float ts[1536];      // tbias row for this window
  __shared__ bf16 qs[64 * 72];    // q[token][d] (pre-scaled)
  __shared__ bf16 kts[64 * 72];   // k[token][d]
  __shared__ bf16 vts[64 * 72];   // v^T [d][token]
  __shared__ bf16 ps[64 * 72];    // P[token][token] bf16

  const int b = blockIdx.x;
  const int t = threadIdx.x, l = t & 63, w = t >> 6;
  const int li = l & 15, lg = l >> 4, kl = lg << 3;

  {  // stage x window fp32 -> bf16 LDS
    const float* xb = x + (size_t)b * (64 * 512);
#pragma unroll
    for (int i = 0; i < 32; ++i) {
      int f4 = t + (i << 8);
      int n = f4 >> 7, c4 = (f4 & 127) << 2;
      f32x4 v = *((const f32x4*)&xb[n * 512 + c4]);
      bf16x4 pk;
      pk[0] = (bf16)v[0]; pk[1] = (bf16)v[1]; pk[2] = (bf16)v[2]; pk[3] = (bf16)v[3];
      *((bf16x4*)&xs[n * 520 + c4]) = pk;
    }
    const float* tb = tbias + (size_t)b * 1536;
    for (int i = t; i < 1536; i += 256) ts[i] = tb[i];
  }

  // rel-pos table offsets (idx*8) for this lane's 16 (row,col) S entries
  int rpidx[4][4];
#pragma unroll
  for (int ct = 0; ct < 4; ++ct)
#pragma unroll
    for (int r = 0; r < 4; ++r) {
      int n = 16 * w + (lg << 2) + r, m = 16 * ct + li;
      rpidx[ct][r] = (((n >> 3) - (m >> 3) + 7) * 15 + ((n & 7) - (m & 7) + 7)) * 8;
    }
  __syncthreads();

  for (int h = 0; h < 8; ++h) {
    // --- qkv GEMM: wave w computes local cols [48w, 48w+48), all 64 rows
    f32x4 acc[3][4] = {};
    int j0[3];
#pragma unroll
    for (int ct = 0; ct < 3; ++ct) {
      int lc = 48 * w + 16 * ct;
      j0[ct] = (lc >> 6) * 512 + h * 64 + (lc & 63);  // W col = sec*512 + h*64 + d
    }
#pragma unroll 4
    for (int ks = 0; ks < 16; ++ks) {
      int k0 = ks << 5;
      bf16x8 af[4];
#pragma unroll
      for (int mt = 0; mt < 4; ++mt)
        af[mt] = *((const bf16x8*)&xs[(mt * 16 + li) * 520 + k0 + kl]);
#pragma unroll
      for (int ct = 0; ct < 3; ++ct) {
        bf16x8 bw = *((const bf16x8*)&w1t[(size_t)(j0[ct] + li) * 512 + k0 + kl]);
#pragma unroll
        for (int mt = 0; mt < 4; ++mt)
          acc[ct][mt] = MFMA(af[mt], bw, acc[ct][mt]);
      }
    }
    // --- epilogue: +tbias, scatter to q / k / v^T LDS tiles
#pragma unroll
    for (int ct = 0; ct < 3; ++ct) {
      int lc = 48 * w + 16 * ct;
      int sec = lc >> 6, dc = lc & 63;
      float tb = ts[j0[ct] + li];
#pragma unroll
      for (int mt = 0; mt < 4; ++mt) {
        int row0 = mt * 16 + (lg << 2);
        if (sec == 0) {
#pragma unroll
          for (int r = 0; r < 4; ++r)
            qs[(row0 + r) * 72 + dc + li] = (bf16)((acc[ct][mt][r] + tb) * 0.125f);
        } else if (sec == 1) {
#pragma unroll
          for (int r = 0; r < 4; ++r)
            kts[(row0 + r) * 72 + dc + li] = (bf16)(acc[ct][mt][r] + tb);
        } else {
          bf16x4 pk;
#pragma unroll
          for (int r = 0; r < 4; ++r) pk[r] = (bf16)(acc[ct][mt][r] + tb);
          *((bf16x4*)&vts[(dc + li) * 72 + row0]) = pk;  // transposed store
        }
      }
    }
    __syncthreads();

    // --- S = (q*scale) @ k^T : wave owns rows [16w, 16w+16)
    f32x4 accS[4] = {};
#pragma unroll
    for (int kk = 0; kk < 2; ++kk) {
      bf16x8 aq = *((const bf16x8*)&qs[(16 * w + li) * 72 + kk * 32 + kl]);
#pragma unroll
      for (int ct = 0; ct < 4; ++ct) {
        bf16x8 bk = *((const bf16x8*)&kts[(16 * ct + li) * 72 + kk * 32 + kl]);
        accS[ct] = MFMA(aq, bk, accS[ct]);
      }
    }
    // --- softmax with rel-pos bias (rows wave-resident; 16-lane reduce)
    const float* rpbh = rpb + h;
    float sv[4][4], rsum[4];
#pragma unroll
    for (int ct = 0; ct < 4; ++ct)
#pragma unroll
      for (int r = 0; r < 4; ++r)
        sv[ct][r] = accS[ct][r] + rpbh[rpidx[ct][r]];
#pragma unroll
    for (int r = 0; r < 4; ++r) {
      float m = fmaxf(fmaxf(sv[0][r], sv[1][r]), fmaxf(sv[2][r], sv[3][r]));
      m = fmaxf(m, __shfl_xor(m, 1));
      m = fmaxf(m, __shfl_xor(m, 2));
      m = fmaxf(m, __shfl_xor(m, 4));
      m = fmaxf(m, __shfl_xor(m, 8));
      float s = 0.f;
#pragma unroll
      for (int ct = 0; ct < 4; ++ct) {
        float p = __expf(sv[ct][r] - m);
        sv[ct][r] = p;
        s += p;
      }
      s += __shfl_xor(s, 1);
      s += __shfl_xor(s, 2);
      s += __shfl_xor(s, 4);
      s += __shfl_xor(s, 8);
      rsum[r] = s;
    }
#pragma unroll
    for (int ct = 0; ct < 4; ++ct)
#pragma unroll
      for (int r = 0; r < 4; ++r)
        ps[(16 * w + (lg << 2) + r) * 72 + 16 * ct + li] = (bf16)sv[ct][r];

    // --- O = P @ V (ps rows are wave-local: no barrier needed before read)
    f32x4 accO[4] = {};
#pragma unroll
    for (int kk = 0; kk < 2; ++kk) {
      bf16x8 ap = *((const bf16x8*)&ps[(16 * w + li) * 72 + kk * 32 + kl]);
#pragma unroll
      for (int ct = 0; ct < 4; ++ct) {
        bf16x8 bv = *((const bf16x8*)&vts[(16 * ct + li) * 72 + kk * 32 + kl]);
        accO[ct] = MFMA(ap, bv, accO[ct]);
      }
    }
    bf16* ob = attn_out + (size_t)b * (64 * 512) + h * 64;
    float rinv[4];
#pragma unroll
    for (int r = 0; r < 4; ++r) rinv[r] = 1.0f / rsum[r];
#pragma unroll
    for (int ct = 0; ct < 4; ++ct)
#pragma unroll
      for (int r = 0; r < 4; ++r)
        ob[(size_t)(16 * w + (lg << 2) + r) * 512 + 16 * ct + li] =
            (bf16)(accO[ct][r] * rinv[r]);
    __syncthreads();  // protect LDS tiles before next head overwrites
  }
}

extern "C" void kernel_launch(void* const* d_in, const int* in_sizes, int n_in,
                              void* d_out, int out_size, void* d_ws, size_t ws_size,
                              hipStream_t stream) {
  (void)in_sizes; (void)n_in; (void)out_size; (void)ws_size;
  const float* x       = (const float*)d_in[0];
  const float* temb    = (const float*)d_in[1];
  const float* w_qkv   = (const float*)d_in[2];
  const float* b_qkv   = (const float*)d_in[3];
  const float* w_qkv_t = (const float*)d_in[4];
  const float* w_proj  = (const float*)d_in[5];
  const float* b_proj  = (const float*)d_in[6];
  const float* rpb     = (const float*)d_in[7];
  float* out = (float*)d_out;

  char* ws = (char*)d_ws;
  size_t off = 0;
  auto take = [&](size_t bytes) {
    void* p = ws + off;
    off += (bytes + 255) & ~(size_t)255;
    return p;
  };
  bf16* w1t  = (bf16*)take((size_t)1536 * 512 * 2);   // w_qkv^T bf16
  bf16* w3t  = (bf16*)take((size_t)1536 * 512 * 2);   // w_qkv_t^T bf16
  bf16* w2t  = (bf16*)take((size_t)512 * 512 * 2);    // w_proj^T bf16
  float* tb  = (float*)take((size_t)2048 * 1536 * 4); // temb@w_qkv_t + b_qkv
  bf16* attn = (bf16*)take((size_t)131072 * 512 * 2); // attention output bf16

  transpose_cast<<<(512 * 1536 + 255) / 256, 256, 0, stream>>>(w_qkv, w1t, 512, 1536);
  transpose_cast<<<(512 * 1536 + 255) / 256, 256, 0, stream>>>(w_qkv_t, w3t, 512, 1536);
  transpose_cast<<<(512 * 512 + 255) / 256, 256, 0, stream>>>(w_proj, w2t, 512, 512);

  gemm_bt_bias<true><<<dim3(2048 / 128, 1536 / 128), 256, 0, stream>>>(
      temb, w3t, b_qkv, tb, 2048, 1536, 512);

  fused_qkv_attn<<<2048, 256, 0, stream>>>(x, w1t, tb, rpb, attn);

  gemm_bt_bias<false><<<dim3(131072 / 128, 512 / 128), 256, 0, stream>>>(
      attn, w2t, b_proj, out, 131072, 512, 512);
}

// Round 2
// 757.840 us; speedup vs baseline: 1.2344x; 1.2344x over previous
//
#include <hip/hip_runtime.h>

typedef __bf16 bf16;
typedef __bf16 bf16x4 __attribute__((ext_vector_type(4)));
typedef __bf16 bf16x8 __attribute__((ext_vector_type(8)));
typedef float f32x4 __attribute__((ext_vector_type(4)));

#define MFMA(a, b, c) __builtin_amdgcn_mfma_f32_16x16x32_bf16((a), (b), (c), 0, 0, 0)

// ---------------- prep: out[c][r] = bf16(in[r][c]) ----------------
__global__ void transpose_cast(const float* __restrict__ in, bf16* __restrict__ out,
                               int R, int C) {
  int i = blockIdx.x * 256 + threadIdx.x;
  if (i >= R * C) return;
  int r = i / C, c = i - r * C;
  out[(size_t)c * R + r] = (bf16)in[i];
}

// ---------------- GEMM: C[M][N] = A[M][K] @ Bt[N][K]^T + bias[N] ----------------
template <bool AF32>
__global__ __launch_bounds__(256) void gemm_bt_bias(
    const void* __restrict__ Ap, const bf16* __restrict__ Bt,
    const float* __restrict__ bias, float* __restrict__ C,
    int M, int N, int K) {
  __shared__ bf16 lA[128 * 32];
  __shared__ bf16 lB[128 * 32];
  const int t = threadIdx.x, l = t & 63;
  const int w = t >> 6, wr = w >> 1, wc = w & 1;
  const int li = l & 15, kl = (l >> 4) << 3;
  const long bm0 = (long)blockIdx.x * 128, bn0 = (long)blockIdx.y * 128;
  f32x4 acc[4][4] = {};
  for (int ks = 0; ks < (K >> 5); ++ks) {
    const int k0 = ks << 5;
    __syncthreads();
#pragma unroll
    for (int i = 0; i < 2; ++i) {
      int u = t + (i << 8);
      int row = u >> 2, kc = (u & 3) << 3;
      if constexpr (AF32) {
        const float* ag = (const float*)Ap + (bm0 + row) * K + k0 + kc;
        f32x4 v0 = *((const f32x4*)ag);
        f32x4 v1 = *((const f32x4*)(ag + 4));
        bf16x8 pk;
        pk[0] = (bf16)v0[0]; pk[1] = (bf16)v0[1]; pk[2] = (bf16)v0[2]; pk[3] = (bf16)v0[3];
        pk[4] = (bf16)v1[0]; pk[5] = (bf16)v1[1]; pk[6] = (bf16)v1[2]; pk[7] = (bf16)v1[3];
        *((bf16x8*)&lA[u << 3]) = pk;
      } else {
        *((bf16x8*)&lA[u << 3]) =
            *((const bf16x8*)((const bf16*)Ap + (bm0 + row) * K + k0 + kc));
      }
      *((bf16x8*)&lB[u << 3]) = *((const bf16x8*)&Bt[(bn0 + row) * K + k0 + kc]);
    }
    __syncthreads();
    bf16x8 af[4], bfr[4];
#pragma unroll
    for (int mt = 0; mt < 4; ++mt)
      af[mt] = *((const bf16x8*)&lA[(wr * 64 + mt * 16 + li) * 32 + kl]);
#pragma unroll
    for (int nt = 0; nt < 4; ++nt)
      bfr[nt] = *((const bf16x8*)&lB[(wc * 64 + nt * 16 + li) * 32 + kl]);
#pragma unroll
    for (int mt = 0; mt < 4; ++mt)
#pragma unroll
      for (int nt = 0; nt < 4; ++nt)
        acc[mt][nt] = MFMA(af[mt], bfr[nt], acc[mt][nt]);
  }
#pragma unroll
  for (int mt = 0; mt < 4; ++mt)
#pragma unroll
    for (int nt = 0; nt < 4; ++nt) {
      long col = bn0 + wc * 64 + nt * 16 + li;
      float bv = bias[col];
#pragma unroll
      for (int r = 0; r < 4; ++r) {
        long row = bm0 + wr * 64 + mt * 16 + ((l >> 4) << 2) + r;
        C[row * N + col] = acc[mt][nt][r] + bv;
      }
    }
}

// ---------------- fused per-window qkv + attention ----------------
// grid = 2048 windows, 512 threads = 8 waves. Loop over 4 head-PAIRS.
// GEMM phase: 8 waves x 3 col-tiles cover the pair's 384 qkv cols (no
// redundant W loads). Attention phase: 8 waves = 2 heads x 4 row-strips.
// P is written into qs (q no longer needed) -> no separate ps buffer.
__global__ __launch_bounds__(512) void fused_qkv_attn(
    const float* __restrict__ x, const bf16* __restrict__ w1t,
    const float* __restrict__ tbias, const float* __restrict__ rpb,
    bf16* __restrict__ attn_out) {
  __shared__ bf16 xs[64 * 520];      // x window, bf16, padded
  __shared__ float ts[1536];         // tbias row
  __shared__ bf16 qs[2][64 * 72];    // q (pre-scaled) / later P, per head
  __shared__ bf16 kts[2][64 * 72];   // k
  __shared__ bf16 vts[2][64 * 72];   // v^T

  const int b = blockIdx.x;
  const int t = threadIdx.x, l = t & 63, w = t >> 6;   // w in 0..7
  const int li = l & 15, lg = l >> 4, kl = lg << 3;
  const int strip = w & 3, hl = w >> 2;                // attention role

  {  // stage x window fp32 -> bf16 LDS (512 threads)
    const float* xb = x + (size_t)b * (64 * 512);
#pragma unroll
    for (int i = 0; i < 16; ++i) {
      int f4 = t + (i << 9);
      int n = f4 >> 7, c4 = (f4 & 127) << 2;
      f32x4 v = *((const f32x4*)&xb[n * 512 + c4]);
      bf16x4 pk;
      pk[0] = (bf16)v[0]; pk[1] = (bf16)v[1]; pk[2] = (bf16)v[2]; pk[3] = (bf16)v[3];
      *((bf16x4*)&xs[n * 520 + c4]) = pk;
    }
    const float* tb = tbias + (size_t)b * 1536;
    for (int i = t; i < 1536; i += 512) ts[i] = tb[i];
  }

  // GEMM col assignment: wave w owns pair-local cols [48w, 48w+48)
  int chh[3], csec[3], cdc[3];
#pragma unroll
  for (int ct = 0; ct < 3; ++ct) {
    int lc = 48 * w + 16 * ct;          // 0..383
    int hh = lc >= 192;                 // which head of the pair
    chh[ct] = hh;
    csec[ct] = (lc - 192 * hh) >> 6;    // 0=q 1=k 2=v
    cdc[ct] = lc & 63;                  // d within head
  }

  // rel-pos table offsets for this lane's 16 S entries
  int rpidx[4][4];
#pragma unroll
  for (int ct = 0; ct < 4; ++ct)
#pragma unroll
    for (int r = 0; r < 4; ++r) {
      int n = 16 * strip + (lg << 2) + r, m = 16 * ct + li;
      rpidx[ct][r] = (((n >> 3) - (m >> 3) + 7) * 15 + ((n & 7) - (m & 7) + 7)) * 8;
    }
  __syncthreads();

  for (int hp = 0; hp < 4; ++hp) {
    // --- qkv GEMM for this head-pair
    f32x4 acc[3][4] = {};
    int j0[3];
#pragma unroll
    for (int ct = 0; ct < 3; ++ct)
      j0[ct] = csec[ct] * 512 + (hp * 2 + chh[ct]) * 64 + cdc[ct];
#pragma unroll 4
    for (int ks = 0; ks < 16; ++ks) {
      int k0 = ks << 5;
      bf16x8 af[4];
#pragma unroll
      for (int mt = 0; mt < 4; ++mt)
        af[mt] = *((const bf16x8*)&xs[(mt * 16 + li) * 520 + k0 + kl]);
#pragma unroll
      for (int ct = 0; ct < 3; ++ct) {
        bf16x8 bw = *((const bf16x8*)&w1t[(size_t)(j0[ct] + li) * 512 + k0 + kl]);
#pragma unroll
        for (int mt = 0; mt < 4; ++mt)
          acc[ct][mt] = MFMA(af[mt], bw, acc[ct][mt]);
      }
    }
    // --- epilogue: +tbias, scatter to q / k / v^T LDS tiles
#pragma unroll
    for (int ct = 0; ct < 3; ++ct) {
      int hh = chh[ct], sec = csec[ct], dc = cdc[ct];
      float tb = ts[j0[ct] + li];
#pragma unroll
      for (int mt = 0; mt < 4; ++mt) {
        int row0 = mt * 16 + (lg << 2);
        if (sec == 0) {
#pragma unroll
          for (int r = 0; r < 4; ++r)
            qs[hh][(row0 + r) * 72 + dc + li] = (bf16)((acc[ct][mt][r] + tb) * 0.125f);
        } else if (sec == 1) {
#pragma unroll
          for (int r = 0; r < 4; ++r)
            kts[hh][(row0 + r) * 72 + dc + li] = (bf16)(acc[ct][mt][r] + tb);
        } else {
          bf16x4 pk;
#pragma unroll
          for (int r = 0; r < 4; ++r) pk[r] = (bf16)(acc[ct][mt][r] + tb);
          *((bf16x4*)&vts[hh][(dc + li) * 72 + row0]) = pk;
        }
      }
    }
    __syncthreads();

    // --- S = (q*scale) @ k^T : wave = (head hl, rows [16*strip, +16))
    f32x4 accS[4] = {};
#pragma unroll
    for (int kk = 0; kk < 2; ++kk) {
      bf16x8 aq = *((const bf16x8*)&qs[hl][(16 * strip + li) * 72 + kk * 32 + kl]);
#pragma unroll
      for (int ct = 0; ct < 4; ++ct) {
        bf16x8 bk = *((const bf16x8*)&kts[hl][(16 * ct + li) * 72 + kk * 32 + kl]);
        accS[ct] = MFMA(aq, bk, accS[ct]);
      }
    }
    // --- softmax with rel-pos bias
    const int h = hp * 2 + hl;
    const float* rpbh = rpb + h;
    float sv[4][4], rsum[4];
#pragma unroll
    for (int ct = 0; ct < 4; ++ct)
#pragma unroll
      for (int r = 0; r < 4; ++r)
        sv[ct][r] = accS[ct][r] + rpbh[rpidx[ct][r]];
#pragma unroll
    for (int r = 0; r < 4; ++r) {
      float m = fmaxf(fmaxf(sv[0][r], sv[1][r]), fmaxf(sv[2][r], sv[3][r]));
      m = fmaxf(m, __shfl_xor(m, 1));
      m = fmaxf(m, __shfl_xor(m, 2));
      m = fmaxf(m, __shfl_xor(m, 4));
      m = fmaxf(m, __shfl_xor(m, 8));
      float s = 0.f;
#pragma unroll
      for (int ct = 0; ct < 4; ++ct) {
        float p = __expf(sv[ct][r] - m);
        sv[ct][r] = p;
        s += p;
      }
      s += __shfl_xor(s, 1);
      s += __shfl_xor(s, 2);
      s += __shfl_xor(s, 4);
      s += __shfl_xor(s, 8);
      rsum[r] = s;
    }
    // write P into qs (this wave's strip rows only; q already consumed)
#pragma unroll
    for (int ct = 0; ct < 4; ++ct)
#pragma unroll
      for (int r = 0; r < 4; ++r)
        qs[hl][(16 * strip + (lg << 2) + r) * 72 + 16 * ct + li] = (bf16)sv[ct][r];

    // --- O = P @ V
    f32x4 accO[4] = {};
#pragma unroll
    for (int kk = 0; kk < 2; ++kk) {
      bf16x8 ap = *((const bf16x8*)&qs[hl][(16 * strip + li) * 72 + kk * 32 + kl]);
#pragma unroll
      for (int ct = 0; ct < 4; ++ct) {
        bf16x8 bv = *((const bf16x8*)&vts[hl][(16 * ct + li) * 72 + kk * 32 + kl]);
        accO[ct] = MFMA(ap, bv, accO[ct]);
      }
    }
    bf16* ob = attn_out + (size_t)b * (64 * 512) + h * 64;
    float rinv[4];
#pragma unroll
    for (int r = 0; r < 4; ++r) rinv[r] = 1.0f / rsum[r];
#pragma unroll
    for (int ct = 0; ct < 4; ++ct)
#pragma unroll
      for (int r = 0; r < 4; ++r)
        ob[(size_t)(16 * strip + (lg << 2) + r) * 512 + 16 * ct + li] =
            (bf16)(accO[ct][r] * rinv[r]);
    __syncthreads();  // protect LDS tiles before next pair overwrites
  }
}

extern "C" void kernel_launch(void* const* d_in, const int* in_sizes, int n_in,
                              void* d_out, int out_size, void* d_ws, size_t ws_size,
                              hipStream_t stream) {
  (void)in_sizes; (void)n_in; (void)out_size; (void)ws_size;
  const float* x       = (const float*)d_in[0];
  const float* temb    = (const float*)d_in[1];
  const float* w_qkv   = (const float*)d_in[2];
  const float* b_qkv   = (const float*)d_in[3];
  const float* w_qkv_t = (const float*)d_in[4];
  const float* w_proj  = (const float*)d_in[5];
  const float* b_proj  = (const float*)d_in[6];
  const float* rpb     = (const float*)d_in[7];
  float* out = (float*)d_out;

  char* ws = (char*)d_ws;
  size_t off = 0;
  auto take = [&](size_t bytes) {
    void* p = ws + off;
    off += (bytes + 255) & ~(size_t)255;
    return p;
  };
  bf16* w1t  = (bf16*)take((size_t)1536 * 512 * 2);
  bf16* w3t  = (bf16*)take((size_t)1536 * 512 * 2);
  bf16* w2t  = (bf16*)take((size_t)512 * 512 * 2);
  float* tb  = (float*)take((size_t)2048 * 1536 * 4);
  bf16* attn = (bf16*)take((size_t)131072 * 512 * 2);

  transpose_cast<<<(512 * 1536 + 255) / 256, 256, 0, stream>>>(w_qkv, w1t, 512, 1536);
  transpose_cast<<<(512 * 1536 + 255) / 256, 256, 0, stream>>>(w_qkv_t, w3t, 512, 1536);
  transpose_cast<<<(512 * 512 + 255) / 256, 256, 0, stream>>>(w_proj, w2t, 512, 512);

  gemm_bt_bias<true><<<dim3(2048 / 128, 1536 / 128), 256, 0, stream>>>(
      temb, w3t, b_qkv, tb, 2048, 1536, 512);

  fused_qkv_attn<<<2048, 512, 0, stream>>>(x, w1t, tb, rpb, attn);

  gemm_bt_bias<false><<<dim3(131072 / 128, 512 / 128), 256, 0, stream>>>(
      attn, w2t, b_proj, out, 131072, 512, 512);
}